// Round 7
// baseline (12.728 us; speedup 1.0000x reference)
//
#include <hip/hip_runtime.h>
#include <hip/hip_bf16.h>

// h[d,t] = sum_o R[d,o] * lam[d,o]^t,  lam = exp(-exp(p+gamma))
// D=2048, ORDER=64, L=2048. Output (1, D, L) float32.
//
// MFMA form: t = 1024*th + 32*t1 + t0;  t1,t0 in [0,32).
//   H[t1,t0] = sum_o (reff[o] * lam^(32*t1)) * lam^t0,
//   reff = R (th=0)  or  R*lam^1024 (th=1).
// One wave per (d, th): 4096 waves, one 32x32 C tile each, K=64 in 4
// steps of v_mfma_f32_32x32x16_bf16, bf16 hi/lo split (3 products).
//
// Layouts (gfx950 32x32x16): A: row=lane&31, k=8*(lane>>5)+j
//                            B: col=lane&31, k=8*(lane>>5)+j
//                            C: col=lane&31, row=(r&3)+8*(r>>2)+4*(lane>>5)

#define DMODEL 2048
#define ORDER  64
#define SEQLEN 2048

typedef __attribute__((ext_vector_type(8))) __bf16 bf16x8;
typedef __attribute__((ext_vector_type(16))) float f32x16;

__global__ __launch_bounds__(256) void imf_mfma_kernel(
    const float* __restrict__ gamma,
    const float* __restrict__ R,
    const float* __restrict__ p,
    float* __restrict__ out)
{
    const int tid   = threadIdx.x;
    const int wave  = tid >> 6;
    const int lane  = tid & 63;
    const int dslot = wave >> 1;            // which of the block's 2 d's
    const int th    = wave & 1;             // t-half
    const int d     = blockIdx.x * 2 + dslot;

    __shared__ float4 cst[2][ORDER];        // {gl2, r, r*lam^1024, 0}

    // phase 0: 128 threads compute the block's 2x64 mode constants
    if (tid < 128) {
        const int i = blockIdx.x * 128 + tid;     // d*64 + o
        const float LOG2E = 1.44269504088896340736f;
        const float gg = gamma[i];
        const float pp = p[i];
        const float rr = R[i];
        const float gl2 = -__builtin_amdgcn_exp2f((pp + gg) * LOG2E) * LOG2E;
        const float rl  = rr * __builtin_amdgcn_exp2f(gl2 * 1024.0f);
        cst[tid >> 6][tid & 63] = make_float4(gl2, rr, rl, 0.0f);
    }
    __syncthreads();

    const int   row  = lane & 31;           // A row (t1) == B col (t0)
    const int   hl   = lane >> 5;
    const float frow = (float)row;

    f32x16 acc;
#pragma unroll
    for (int r = 0; r < 16; ++r) acc[r] = 0.0f;

#pragma unroll
    for (int kk = 0; kk < 4; ++kk) {
        const int ob = 16 * kk + 8 * hl;    // this lane's k-chunk base (o)
        bf16x8 ah, al, bh, bl;
#pragma unroll
        for (int j = 0; j < 8; ++j) {
            const float4 c = cst[dslot][ob + j];          // broadcast LDS read
            const float u    = c.x * frow;                // gl2 * t0
            const float b    = __builtin_amdgcn_exp2f(u);          // lam^t0
            const float e32  = __builtin_amdgcn_exp2f(32.0f * u);  // lam^(32*t1)
            const float reff = th ? c.z : c.y;
            const float a    = reff * e32;

            const __bf16 ahj = (__bf16)a;
            const __bf16 bhj = (__bf16)b;
            ah[j] = ahj;  al[j] = (__bf16)(a - (float)ahj);
            bh[j] = bhj;  bl[j] = (__bf16)(b - (float)bhj);
        }
        acc = __builtin_amdgcn_mfma_f32_32x32x16_bf16(ah, bh, acc, 0, 0, 0);
        acc = __builtin_amdgcn_mfma_f32_32x32x16_bf16(al, bh, acc, 0, 0, 0);
        acc = __builtin_amdgcn_mfma_f32_32x32x16_bf16(ah, bl, acc, 0, 0, 0);
    }

    // store: out[d*2048 + 1024*th + 32*t1 + t0]
    float* od = out + (size_t)d * SEQLEN + 1024 * th;
#pragma unroll
    for (int r = 0; r < 16; ++r) {
        const int t1 = (r & 3) + 8 * (r >> 2) + 4 * hl;
        od[32 * t1 + row] = acc[r];
    }
}

extern "C" void kernel_launch(void* const* d_in, const int* in_sizes, int n_in,
                              void* d_out, int out_size, void* d_ws, size_t ws_size,
                              hipStream_t stream) {
    const float* gamma = (const float*)d_in[0];
    const float* R     = (const float*)d_in[1];
    const float* p     = (const float*)d_in[2];
    float* out = (float*)d_out;

    imf_mfma_kernel<<<dim3(DMODEL / 2), dim3(256), 0, stream>>>(gamma, R, p, out);
}

// Round 8
// 11.002 us; speedup vs baseline: 1.1569x; 1.1569x over previous
//
#include <hip/hip_runtime.h>
#include <hip/hip_bf16.h>

// h[d,t] = sum_o R[d,o] * lam[d,o]^t,  lam = exp(-exp(p+gamma))
// D=2048, ORDER=64, L=2048. Output (1, D, L) float32.
//
// MFMA form: t = 32*t1 + t0, t1 in [0,64), t0 in [0,32).
//   H[t1,t0] = sum_o A[t1,o]*B[o,t0];  A = reff*lam^(32*t1), B = lam^t0.
// One wave per d, BOTH t1-tiles per wave (max fragment reuse):
//   tile0: reff = R;  tile1: reff = R*lam^1024 (folded into const record).
// SINGLE bf16 product (no hi/lo split): 8 MFMA/wave, ~8 inst per j.
//
// Layouts (gfx950 32x32x16): A: row=lane&31, k=8*(lane>>5)+j
//                            B: col=lane&31, k=8*(lane>>5)+j
//                            C: col=lane&31, row=(r&3)+8*(r>>2)+4*(lane>>5)

#define DMODEL 2048
#define ORDER  64
#define SEQLEN 2048

typedef __attribute__((ext_vector_type(8))) __bf16 bf16x8;
typedef __attribute__((ext_vector_type(16))) float f32x16;

__global__ __launch_bounds__(256) void imf_mfma_kernel(
    const float* __restrict__ gamma,
    const float* __restrict__ R,
    const float* __restrict__ p,
    float* __restrict__ out)
{
    const int tid  = threadIdx.x;
    const int wave = tid >> 6;
    const int lane = tid & 63;
    const int d    = blockIdx.x * 4 + wave;

    __shared__ float4 cst[4][ORDER];    // {gl2, r, r*lam^1024, 0}

    // phase 0: one thread per (d,o); coalesced loads, 2 exp2
    {
        const int i = blockIdx.x * 256 + tid;      // d*64 + o
        const float LOG2E = 1.44269504088896340736f;
        const float gg = gamma[i];
        const float pp = p[i];
        const float rr = R[i];
        const float gl2 = -__builtin_amdgcn_exp2f((pp + gg) * LOG2E) * LOG2E;
        const float rl  = rr * __builtin_amdgcn_exp2f(gl2 * 1024.0f);
        cst[wave][lane] = make_float4(gl2, rr, rl, 0.0f);
    }
    __syncthreads();

    const int   row  = lane & 31;       // A row (t1 in tile) == B col (t0)
    const int   hl   = lane >> 5;
    const float frow = (float)row;

    f32x16 acc0, acc1;
#pragma unroll
    for (int r = 0; r < 16; ++r) { acc0[r] = 0.0f; acc1[r] = 0.0f; }

#pragma unroll
    for (int kk = 0; kk < 4; ++kk) {
        const int ob = 16 * kk + 8 * hl;
        bf16x8 ah, a2h, bh;
#pragma unroll
        for (int j = 0; j < 8; ++j) {
            const float4 c  = cst[wave][ob + j];           // broadcast LDS read
            const float u   = c.x * frow;                  // gl2 * t0
            const float b   = __builtin_amdgcn_exp2f(u);           // lam^t0
            const float e32 = __builtin_amdgcn_exp2f(32.0f * u);   // lam^(32*t1)
            ah[j]  = (__bf16)(c.y * e32);                  // R * lam^(32*t1)
            a2h[j] = (__bf16)(c.z * e32);                  // tile1: *lam^1024
            bh[j]  = (__bf16)b;
        }
        acc0 = __builtin_amdgcn_mfma_f32_32x32x16_bf16(ah,  bh, acc0, 0, 0, 0);
        acc1 = __builtin_amdgcn_mfma_f32_32x32x16_bf16(a2h, bh, acc1, 0, 0, 0);
    }

    // store: out[d*2048 + 32*t1 + t0]; tile1 at +1024
    float* od = out + (size_t)d * SEQLEN;
#pragma unroll
    for (int r = 0; r < 16; ++r) {
        const int t1 = (r & 3) + 8 * (r >> 2) + 4 * hl;
        od[32 * t1 + row]          = acc0[r];
        od[32 * t1 + 1024 + row]   = acc1[r];
    }
}

extern "C" void kernel_launch(void* const* d_in, const int* in_sizes, int n_in,
                              void* d_out, int out_size, void* d_ws, size_t ws_size,
                              hipStream_t stream) {
    const float* gamma = (const float*)d_in[0];
    const float* R     = (const float*)d_in[1];
    const float* p     = (const float*)d_in[2];
    float* out = (float*)d_out;

    imf_mfma_kernel<<<dim3(DMODEL / 4), dim3(256), 0, stream>>>(gamma, R, p, out);
}